// Round 11
// baseline (174.708 us; speedup 1.0000x reference)
//
#include <hip/hip_runtime.h>

#define N_NODES 10000
#define N_EDGES 30000
#define DIN     64
#define EDIM    16
#define H1      128
#define H2      64
#define C_OUT   10

typedef __bf16 bfrag __attribute__((ext_vector_type(8)));
typedef float  f32x4 __attribute__((ext_vector_type(4)));
typedef ushort ushort8 __attribute__((ext_vector_type(8)));

__device__ __forceinline__ ushort f2bf(float f) {
    union { float f; unsigned u; } x; x.f = f;
    unsigned r = x.u + 0x7fffu + ((x.u >> 16) & 1u);   // RNE; inputs finite
    return (ushort)(r >> 16);
}
__device__ __forceinline__ float bf2f(ushort s) {
    union { unsigned u; float f; } x; x.u = ((unsigned)s) << 16;
    return x.f;
}

// ---------------------------------------------------------------------------
// K3 (self-contained): per block —
//   1) stage W1 -> LDS bf16 k-major (pad 72), B1-slice y -> LDS (pad 136,
//      permuted rows c'=o*16+k so the main-GEMM store is the G1t[n][o][k]
//      layout), b1 -> LDS.
//   2) h-tile[128x128] = relu(x@W1+b1) via MFMA -> LDS hL (pad 136).
//   3) main GEMM: C = hL @ B1-slice; coalesced stores (R8-proven epilogue).
// y==16/17 blocks also zero agg1/agg2 (visible after HW boundary flush).
__global__ __launch_bounds__(256) void k3_mfma(
        const float* __restrict__ x, const float* __restrict__ W1,
        const float* __restrict__ b1,
        const float* __restrict__ We1, const float* __restrict__ root1,
        const float* __restrict__ be1, const float* __restrict__ bias1,
        ushort* __restrict__ G1t, float* __restrict__ hrb1, float* __restrict__ hb1,
        float* __restrict__ agg1, float* __restrict__ agg2) {
    __shared__ ushort W1L[128 * 72];    // [o][i], pad 72: 16B-aligned rows, 2-way banks
    __shared__ ushort B1L[64 * 136];    // [c][i], pad 136
    __shared__ ushort hL[128 * 136];    // [row][o], pad 136
    __shared__ float  b1L[H1];
    int t = threadIdx.x;
    int wave = t >> 6, lane = t & 63;
    int quad = lane >> 4, lrow = lane & 15;
    int y = blockIdx.y, mx = blockIdx.x;

    // zeroing side-duty
    if (y == 17) {
        for (int i = mx * 256 + t; i < 160000; i += 79 * 256)
            ((float4*)agg1)[i] = make_float4(0.f, 0.f, 0.f, 0.f);
    } else if (y == 16) {
        for (int i = mx * 256 + t; i < 25000; i += 79 * 256)
            ((float4*)agg2)[i] = make_float4(0.f, 0.f, 0.f, 0.f);
    }

    // ---- stage W1L (coalesced read, scattered LDS write) ----
    for (int idx = t; idx < DIN * H1; idx += 256) {
        int i = idx >> 7, o = idx & 127;        // W1[i][o]
        W1L[o * 72 + i] = f2bf(W1[idx]);
    }
    // ---- stage B1L (permuted gather; L2-amortized across mx) ----
    for (int idx = t; idx < 64 * 128; idx += 256) {
        int c = idx >> 7, i = idx & 127;
        float v;
        if (y < 16) {
            int cg = y * 64 + c;
            v = We1[(size_t)(cg & 15) * (H1 * H2) + i * 64 + (cg >> 4)];
        } else if (y == 16) v = root1[i * 64 + c];
        else                v = be1[i * 64 + c];
        B1L[c * 136 + i] = f2bf(v);
    }
    if (t < H1) b1L[t] = b1[t];
    __syncthreads();

    // ---- h-phase: wave computes its own rows [wave*32, wave*32+32) x 128 ----
    int nb = mx * 128;
    int r0 = nb + wave * 32 + lrow;      if (r0 > N_NODES - 1) r0 = N_NODES - 1;
    int r1 = r0 + 16;                    if (r1 > N_NODES - 1) r1 = N_NODES - 1;
    bfrag xa[2][2];   // [half][kc2]
    #pragma unroll
    for (int half = 0; half < 2; ++half) {
        int rr = half ? r1 : r0;
        #pragma unroll
        for (int kk = 0; kk < 2; ++kk) {
            f32x4 p = *(const f32x4*)(x + (size_t)rr * DIN + kk * 32 + quad * 8);
            f32x4 q = *(const f32x4*)(x + (size_t)rr * DIN + kk * 32 + quad * 8 + 4);
            bfrag a;
            #pragma unroll
            for (int j = 0; j < 4; ++j) { a[j] = (__bf16)p[j]; a[j + 4] = (__bf16)q[j]; }
            xa[half][kk] = a;
        }
    }
    #pragma unroll
    for (int ct2 = 0; ct2 < 8; ++ct2) {
        f32x4 ah0 = {}, ah1 = {};
        #pragma unroll
        for (int kk = 0; kk < 2; ++kk) {
            bfrag b = *reinterpret_cast<const bfrag*>(
                &W1L[(ct2 * 16 + lrow) * 72 + kk * 32 + quad * 8]);
            ah0 = __builtin_amdgcn_mfma_f32_16x16x32_bf16(xa[0][kk], b, ah0, 0, 0, 0);
            ah1 = __builtin_amdgcn_mfma_f32_16x16x32_bf16(xa[1][kk], b, ah1, 0, 0, 0);
        }
        int col = ct2 * 16 + lrow;
        float bv = b1L[col];
        #pragma unroll
        for (int half = 0; half < 2; ++half) {
            #pragma unroll
            for (int r = 0; r < 4; ++r) {
                int rl = wave * 32 + half * 16 + quad * 4 + r;
                float v = (half ? ah1[r] : ah0[r]) + bv;
                hL[rl * 136 + col] = f2bf(fmaxf(v, 0.f));
            }
        }
    }
    // no __syncthreads needed: each wave reads only hL rows it wrote itself;
    // B1L/W1L were synced above. Compiler handles same-wave lgkmcnt.

    // ---- main GEMM: 32 rows x 64 cols per wave ----
    f32x4 acc0[4] = {}, acc1[4] = {};
    #pragma unroll
    for (int kc = 0; kc < 128; kc += 32) {
        bfrag a0 = *reinterpret_cast<const bfrag*>(
            &hL[(wave * 32 + lrow) * 136 + kc + quad * 8]);
        bfrag a1 = *reinterpret_cast<const bfrag*>(
            &hL[(wave * 32 + 16 + lrow) * 136 + kc + quad * 8]);
        #pragma unroll
        for (int ct = 0; ct < 4; ++ct) {
            bfrag b = *reinterpret_cast<const bfrag*>(
                &B1L[(ct * 16 + lrow) * 136 + kc + quad * 8]);
            acc0[ct] = __builtin_amdgcn_mfma_f32_16x16x32_bf16(a0, b, acc0[ct], 0, 0, 0);
            acc1[ct] = __builtin_amdgcn_mfma_f32_16x16x32_bf16(a1, b, acc1[ct], 0, 0, 0);
        }
    }
    int nbase = nb + wave * 32;
    #pragma unroll
    for (int half = 0; half < 2; ++half) {
        int rbase = nbase + half * 16 + quad * 4;
        #pragma unroll
        for (int ct = 0; ct < 4; ++ct) {
            int col = ct * 16 + lrow;
            f32x4 a = half ? acc1[ct] : acc0[ct];
            #pragma unroll
            for (int r = 0; r < 4; ++r) {
                int n = rbase + r;
                if (n >= N_NODES) continue;
                float v = a[r];
                if (y < 16) {
                    G1t[(size_t)n * 1024 + y * 64 + col] = f2bf(v);  // coalesced
                } else if (y == 16) {
                    hrb1[(size_t)n * 64 + col] = v + bias1[col];
                } else {
                    hb1[(size_t)n * 64 + col] = v;
                }
            }
        }
    }
}

// ---------------------------------------------------------------------------
// K4: edge pass 1. 2 edges per wave, lane = output o. G1t[n][o][k] bf16:
// per edge, lane reads 32 contiguous bytes (2 x 16B).
__global__ __launch_bounds__(256) void k4_edge1(
        const float* __restrict__ ea, const int* __restrict__ src_idx,
        const int* __restrict__ dst_idx, const ushort* __restrict__ G1t,
        const float* __restrict__ hb1, float* __restrict__ agg1) {
    int t = threadIdx.x;
    int e0 = blockIdx.x * 8 + (t >> 6) * 2;   // 8 edges/block, 2/wave
    int o = t & 63;
    int s0 = src_idx[e0],     d0 = dst_idx[e0];
    int s1 = src_idx[e0 + 1], d1 = dst_idx[e0 + 1];
    const ushort* g0p = G1t + (size_t)s0 * 1024 + o * 16;
    const ushort* g1p = G1t + (size_t)s1 * 1024 + o * 16;
    ushort8 ga0 = *reinterpret_cast<const ushort8*>(g0p);
    ushort8 ga1 = *reinterpret_cast<const ushort8*>(g0p + 8);
    ushort8 gb0 = *reinterpret_cast<const ushort8*>(g1p);
    ushort8 gb1 = *reinterpret_cast<const ushort8*>(g1p + 8);
    float m0 = hb1[(size_t)s0 * 64 + o];
    float m1 = hb1[(size_t)s1 * 64 + o];
    const float* a0 = ea + (size_t)e0 * 16;   // wave-uniform -> scalar loads
    const float* a1 = a0 + 16;
    #pragma unroll
    for (int k = 0; k < 8; ++k) {
        m0 = fmaf(a0[k], bf2f(ga0[k]), m0);
        m1 = fmaf(a1[k], bf2f(gb0[k]), m1);
    }
    #pragma unroll
    for (int k = 0; k < 8; ++k) {
        m0 = fmaf(a0[k + 8], bf2f(ga1[k]), m0);
        m1 = fmaf(a1[k + 8], bf2f(gb1[k]), m1);
    }
    atomicAdd(&agg1[(size_t)d0 * 64 + o], m0);
    atomicAdd(&agg1[(size_t)d1 * 64 + o], m1);
}

// ---------------------------------------------------------------------------
// K56 (self-contained): stages its B2-slice into LDS (permuted rows
// c'=c*16+k), A = relu(agg1+hrb1) inline; coalesced G2t[n][c][k] store.
__global__ __launch_bounds__(256) void k56_mfma(
        const float* __restrict__ agg1, const float* __restrict__ hrb1,
        const float* __restrict__ We2, const float* __restrict__ be2,
        const float* __restrict__ root2, const float* __restrict__ bias2,
        float* __restrict__ G2t, float* __restrict__ hb2, float* __restrict__ hr2) {
    __shared__ ushort B2L[64 * 72];
    int t = threadIdx.x;
    int wave = t >> 6, lane = t & 63;
    int quad = lane >> 4, lrow = lane & 15;
    int y = blockIdx.y;
    for (int idx = t; idx < 64 * 64; idx += 256) {
        int c = idx >> 6, j = idx & 63;
        int cg = y * 64 + c;
        float v = 0.f;
        if (cg < 160)      v = We2[(size_t)(cg & 15) * 640 + j * 10 + (cg >> 4)];
        else if (cg < 170) v = be2[j * 10 + (cg - 160)];
        else if (cg < 180) v = root2[j * 10 + (cg - 170)];
        B2L[c * 72 + j] = f2bf(v);
    }
    __syncthreads();
    int n0 = blockIdx.x * 64 + wave * 16;
    int arow = n0 + lrow; if (arow > N_NODES - 1) arow = N_NODES - 1;
    f32x4 acc[4] = {};
    #pragma unroll
    for (int kc = 0; kc < 64; kc += 32) {
        size_t off = (size_t)arow * 64 + kc + quad * 8;
        f32x4 p0 = *(const f32x4*)(agg1 + off);
        f32x4 p1 = *(const f32x4*)(agg1 + off + 4);
        f32x4 q0 = *(const f32x4*)(hrb1 + off);
        f32x4 q1 = *(const f32x4*)(hrb1 + off + 4);
        bfrag a;
        #pragma unroll
        for (int j = 0; j < 4; ++j) {
            a[j]     = (__bf16)fmaxf(p0[j] + q0[j], 0.f);
            a[j + 4] = (__bf16)fmaxf(p1[j] + q1[j], 0.f);
        }
        #pragma unroll
        for (int ct = 0; ct < 4; ++ct) {
            bfrag b = *reinterpret_cast<const bfrag*>(
                &B2L[(ct * 16 + lrow) * 72 + kc + quad * 8]);
            acc[ct] = __builtin_amdgcn_mfma_f32_16x16x32_bf16(a, b, acc[ct], 0, 0, 0);
        }
    }
    #pragma unroll
    for (int ct = 0; ct < 4; ++ct) {
        int cg = y * 64 + ct * 16 + lrow;
        #pragma unroll
        for (int r = 0; r < 4; ++r) {
            int n = n0 + quad * 4 + r;
            if (n >= N_NODES) continue;
            float v = acc[ct][r];
            if (cg < 160)      G2t[(size_t)n * 160 + cg] = v;   // coalesced
            else if (cg < 170) hb2[(size_t)n * 10 + (cg - 160)] = v;
            else if (cg < 180) hr2[(size_t)n * 10 + (cg - 170)] = v + bias2[cg - 170];
        }
    }
}

// ---------------------------------------------------------------------------
// K7: edge pass 2. thread per (edge, class): 10 threads/edge. No fences.
__global__ __launch_bounds__(256) void k7_edge2(
        const float* __restrict__ ea, const int* __restrict__ src_idx,
        const int* __restrict__ dst_idx, const float* __restrict__ G2t,
        const float* __restrict__ hb2, float* __restrict__ agg2) {
    int tid = blockIdx.x * 256 + threadIdx.x;
    if (tid >= N_EDGES * 10) return;
    int e = tid / 10, c = tid - e * 10;
    int s = src_idx[e], d = dst_idx[e];
    float m = hb2[(size_t)s * 10 + c];
    const float* g = G2t + (size_t)s * 160 + c * 16;
    const float* a = ea + (size_t)e * 16;
    f32x4 g0 = *(const f32x4*)g,       g1 = *(const f32x4*)(g + 4);
    f32x4 g2 = *(const f32x4*)(g + 8), g3 = *(const f32x4*)(g + 12);
    f32x4 a0 = *(const f32x4*)a,       a1 = *(const f32x4*)(a + 4);
    f32x4 a2 = *(const f32x4*)(a + 8), a3 = *(const f32x4*)(a + 12);
    #pragma unroll
    for (int k = 0; k < 4; ++k) {
        m = fmaf(a0[k], g0[k], m);
        m = fmaf(a1[k], g1[k], m);
        m = fmaf(a2[k], g2[k], m);
        m = fmaf(a3[k], g3[k], m);
    }
    atomicAdd(&agg2[(size_t)d * 10 + c], m);
}

// ---------------------------------------------------------------------------
// K8: z = agg2 + hr2; out = log_softmax(z)
__global__ void k8_logsoftmax(const float* __restrict__ agg2, const float* __restrict__ hr2,
                              float* __restrict__ out) {
    int n = blockIdx.x * blockDim.x + threadIdx.x;
    if (n >= N_NODES) return;
    float z[10]; float m = -1e30f;
    #pragma unroll
    for (int c = 0; c < 10; ++c) {
        z[c] = agg2[(size_t)n * 10 + c] + hr2[(size_t)n * 10 + c];
        m = fmaxf(m, z[c]);
    }
    float s = 0.f;
    #pragma unroll
    for (int c = 0; c < 10; ++c) s += expf(z[c] - m);
    float ls = logf(s);
    #pragma unroll
    for (int c = 0; c < 10; ++c) out[(size_t)n * 10 + c] = z[c] - m - ls;
}

// ---------------------------------------------------------------------------
extern "C" void kernel_launch(void* const* d_in, const int* in_sizes, int n_in,
                              void* d_out, int out_size, void* d_ws, size_t ws_size,
                              hipStream_t stream) {
    const float* x     = (const float*)d_in[0];
    const float* ea    = (const float*)d_in[1];
    const int*   eidx  = (const int*)d_in[2];
    const float* W1    = (const float*)d_in[3];
    const float* b1    = (const float*)d_in[4];
    const float* We1   = (const float*)d_in[5];
    const float* be1   = (const float*)d_in[6];
    const float* root1 = (const float*)d_in[7];
    const float* bias1 = (const float*)d_in[8];
    const float* We2   = (const float*)d_in[9];
    const float* be2   = (const float*)d_in[10];
    const float* root2 = (const float*)d_in[11];
    const float* bias2 = (const float*)d_in[12];
    float* out = (float*)d_out;

    // workspace layout (float units, all 16B-aligned)
    float* ws = (float*)d_ws;
    ushort* G1t  = (ushort*)ws;                        // 10,240,000 us = 5,120,000 f
    float* hrb1 = ws + 5120000;                        // 640,000
    float* hb1  = hrb1 + 640000;                       // 640,000
    float* agg1 = hb1  + 640000;                       // 640,000
    float* agg2 = agg1 + 640000;                       // 100,000
    float* G2t  = agg2 + 100000;                       // 1,600,000
    float* hb2  = G2t  + 1600000;                      // 100,000
    float* hr2  = hb2  + 100000;                       // 100,000

    k3_mfma<<<dim3(79, 18), 256, 0, stream>>>(x, W1, b1, We1, root1, be1, bias1,
                                              G1t, hrb1, hb1, agg1, agg2);
    k4_edge1<<<3750, 256, 0, stream>>>(ea, eidx, eidx + N_EDGES, G1t, hb1, agg1);
    k56_mfma<<<dim3(157, 3), 256, 0, stream>>>(agg1, hrb1, We2, be2, root2, bias2,
                                               G2t, hb2, hr2);
    k7_edge2<<<1172, 256, 0, stream>>>(ea, eidx, eidx + N_EDGES, G2t, hb2, agg2);
    k8_logsoftmax<<<40, 256, 0, stream>>>(agg2, hr2, out);
}

// Round 12
// 147.210 us; speedup vs baseline: 1.1868x; 1.1868x over previous
//
#include <hip/hip_runtime.h>

#define N_NODES 10000
#define N_EDGES 30000
#define DIN     64
#define EDIM    16
#define H1      128
#define H2      64
#define C_OUT   10

typedef __bf16 bfrag __attribute__((ext_vector_type(8)));
typedef float  f32x4 __attribute__((ext_vector_type(4)));
typedef ushort ushort8 __attribute__((ext_vector_type(8)));

__device__ __forceinline__ ushort f2bf(float f) {
    union { float f; unsigned u; } x; x.f = f;
    unsigned r = x.u + 0x7fffu + ((x.u >> 16) & 1u);   // RNE; inputs finite
    return (ushort)(r >> 16);
}
__device__ __forceinline__ float bf2f(ushort s) {
    union { unsigned u; float f; } x; x.u = ((unsigned)s) << 16;
    return x.f;
}

// ---------------------------------------------------------------------------
// kA: multi-role prep kernel (block-uniform branch) — R8-proven form:
//   blocks [0,1250):      h = relu(x@W1+b1) -> bf16, 8 nodes/block
//   blocks [1250,1826):   pack B1t[1152][128] bf16, PERMUTED: row c'=o*16+k
//   blocks [1826,1874):   pack B2t[192][64]  bf16, PERMUTED: row c'=c*16+k
#define KA_B1   1250
#define KA_B2   (KA_B1 + 576)
#define KA_B3   (KA_B2 + 48)
__global__ __launch_bounds__(256) void kA_prep(
        const float* __restrict__ x, const float* __restrict__ W1,
        const float* __restrict__ b1,
        const float* __restrict__ We1, const float* __restrict__ root1,
        const float* __restrict__ be1,
        const float* __restrict__ We2, const float* __restrict__ be2,
        const float* __restrict__ root2,
        ushort* __restrict__ h_bf, ushort* __restrict__ B1t,
        ushort* __restrict__ B2t) {
    int t = threadIdx.x;
    int bx = blockIdx.x;
    if (bx < KA_B1) {
        __shared__ float w_lds[DIN * H1];
        __shared__ float b_lds[H1];
        __shared__ float x_lds[8][DIN];
        for (int idx = t; idx < DIN * H1 / 4; idx += 256)
            ((float4*)w_lds)[idx] = ((const float4*)W1)[idx];
        if (t < H1) b_lds[t] = b1[t];
        int n0 = bx * 8;
        if (t < 128) {
            int row = t >> 4, c4 = t & 15;
            int n = n0 + row;
            float4 v = make_float4(0.f, 0.f, 0.f, 0.f);
            if (n < N_NODES) v = ((const float4*)(x + (size_t)n * DIN))[c4];
            ((float4*)(x_lds[row]))[c4] = v;
        }
        __syncthreads();
        int nl = t >> 5;
        int o  = (t & 31) * 4;
        int n  = n0 + nl;
        float4 acc = *(const float4*)&b_lds[o];
        #pragma unroll 8
        for (int i = 0; i < DIN; ++i) {
            float xv = x_lds[nl][i];
            float4 w = *(const float4*)&w_lds[i * H1 + o];
            acc.x = fmaf(xv, w.x, acc.x);
            acc.y = fmaf(xv, w.y, acc.y);
            acc.z = fmaf(xv, w.z, acc.z);
            acc.w = fmaf(xv, w.w, acc.w);
        }
        if (n < N_NODES) {
            ushort4 s;
            s.x = f2bf(fmaxf(acc.x, 0.f));
            s.y = f2bf(fmaxf(acc.y, 0.f));
            s.z = f2bf(fmaxf(acc.z, 0.f));
            s.w = f2bf(fmaxf(acc.w, 0.f));
            *(ushort4*)&h_bf[(size_t)n * H1 + o] = s;
        }
    } else if (bx < KA_B2) {
        int idx = (bx - KA_B1) * 256 + t;
        int c = idx >> 7, i = idx & 127;
        float v;
        if (c < 1024) {
            int o = c >> 4, k = c & 15;              // permuted: c' = o*16 + k
            v = We1[(size_t)k * (H1 * H2) + i * 64 + o];
        } else if (c < 1088) v = root1[i * 64 + (c - 1024)];
        else                 v = be1[i * 64 + (c - 1088)];
        B1t[idx] = f2bf(v);
    } else {
        int idx = (bx - KA_B2) * 256 + t;
        int c = idx >> 6, j = idx & 63;
        float v = 0.f;
        if (c < 160) {
            int cc = c >> 4, k = c & 15;             // permuted: c' = cc*16 + k
            v = We2[(size_t)k * 640 + j * 10 + cc];
        }
        else if (c < 170) v = be2[j * 10 + (c - 160)];
        else if (c < 180) v = root2[j * 10 + (c - 170)];
        B2t[idx] = f2bf(v);
    }
}

// ---------------------------------------------------------------------------
// K3: bf16 MFMA GEMM  C[10000 x 1152] = h_bf @ B1; permuted B1t rows make the
// coalesced direct store the G1t[n][o][k] layout. y==16/17 blocks also zero
// agg1/agg2 (visible to later dispatches via HW boundary flush).
__global__ __launch_bounds__(256) void k3_mfma(
        const ushort* __restrict__ h_bf, const ushort* __restrict__ Bt,
        const float* __restrict__ bias1,
        ushort* __restrict__ G1t, float* __restrict__ hrb1, float* __restrict__ hb1,
        float* __restrict__ agg1, float* __restrict__ agg2) {
    int t = threadIdx.x;
    int wave = t >> 6, lane = t & 63;
    int quad = lane >> 4, lrow = lane & 15;
    int y = blockIdx.y;
    int mx = blockIdx.x;
    if (y == 17) {
        for (int i = mx * 256 + t; i < 160000; i += 79 * 256)
            ((float4*)agg1)[i] = make_float4(0.f, 0.f, 0.f, 0.f);
    } else if (y == 16) {
        for (int i = mx * 256 + t; i < 25000; i += 79 * 256)
            ((float4*)agg2)[i] = make_float4(0.f, 0.f, 0.f, 0.f);
    }
    int nbase = mx * 128 + wave * 32;
    int ar0 = nbase + lrow;       if (ar0 > N_NODES - 1) ar0 = N_NODES - 1;
    int ar1 = nbase + 16 + lrow;  if (ar1 > N_NODES - 1) ar1 = N_NODES - 1;
    const ushort* bbase = Bt + (size_t)y * 64 * 128;
    f32x4 acc0[4] = {}, acc1[4] = {};
    #pragma unroll
    for (int kc = 0; kc < 128; kc += 32) {
        bfrag a0 = *reinterpret_cast<const bfrag*>(h_bf + (size_t)ar0 * 128 + kc + quad * 8);
        bfrag a1 = *reinterpret_cast<const bfrag*>(h_bf + (size_t)ar1 * 128 + kc + quad * 8);
        #pragma unroll
        for (int ct = 0; ct < 4; ++ct) {
            bfrag b = *reinterpret_cast<const bfrag*>(
                bbase + (size_t)(ct * 16 + lrow) * 128 + kc + quad * 8);
            acc0[ct] = __builtin_amdgcn_mfma_f32_16x16x32_bf16(a0, b, acc0[ct], 0, 0, 0);
            acc1[ct] = __builtin_amdgcn_mfma_f32_16x16x32_bf16(a1, b, acc1[ct], 0, 0, 0);
        }
    }
    #pragma unroll
    for (int half = 0; half < 2; ++half) {
        int rbase = nbase + half * 16 + quad * 4;
        #pragma unroll
        for (int ct = 0; ct < 4; ++ct) {
            int col = ct * 16 + lrow;
            f32x4 a = half ? acc1[ct] : acc0[ct];
            #pragma unroll
            for (int r = 0; r < 4; ++r) {
                int n = rbase + r;
                if (n >= N_NODES) continue;
                float v = a[r];
                if (y < 16) {
                    G1t[(size_t)n * 1024 + y * 64 + col] = f2bf(v);  // coalesced
                } else if (y == 16) {
                    hrb1[(size_t)n * 64 + col] = v + bias1[col];
                } else {
                    hb1[(size_t)n * 64 + col] = v;
                }
            }
        }
    }
}

// ---------------------------------------------------------------------------
// K4: edge pass 1. 4 edges per wave (16 independent 16B loads in flight for
// latency hiding), lane = output o. G1t[n][o][k] bf16: 32 contig B per edge.
__global__ __launch_bounds__(256) void k4_edge1(
        const float* __restrict__ ea, const int* __restrict__ src_idx,
        const int* __restrict__ dst_idx, const ushort* __restrict__ G1t,
        const float* __restrict__ hb1, float* __restrict__ agg1) {
    int t = threadIdx.x;
    int e0 = blockIdx.x * 16 + (t >> 6) * 4;   // 16 edges/block, 4/wave
    int o = t & 63;
    int s[4], d[4];
    #pragma unroll
    for (int j = 0; j < 4; ++j) { s[j] = src_idx[e0 + j]; d[j] = dst_idx[e0 + j]; }
    ushort8 g0[4], g1[4];
    #pragma unroll
    for (int j = 0; j < 4; ++j) {
        const ushort* gp = G1t + (size_t)s[j] * 1024 + o * 16;
        g0[j] = *reinterpret_cast<const ushort8*>(gp);
        g1[j] = *reinterpret_cast<const ushort8*>(gp + 8);
    }
    float m[4];
    #pragma unroll
    for (int j = 0; j < 4; ++j) m[j] = hb1[(size_t)s[j] * 64 + o];
    const float* a = ea + (size_t)e0 * 16;   // wave-uniform -> broadcast loads
    #pragma unroll
    for (int j = 0; j < 4; ++j) {
        #pragma unroll
        for (int k = 0; k < 8; ++k) m[j] = fmaf(a[j * 16 + k], bf2f(g0[j][k]), m[j]);
        #pragma unroll
        for (int k = 0; k < 8; ++k) m[j] = fmaf(a[j * 16 + 8 + k], bf2f(g1[j][k]), m[j]);
    }
    #pragma unroll
    for (int j = 0; j < 4; ++j)
        atomicAdd(&agg1[(size_t)d[j] * 64 + o], m[j]);
}

// ---------------------------------------------------------------------------
// K56: layer-2 node GEMM via MFMA, A = relu(agg1+hrb1) inline.
// Permuted B2t rows -> direct coalesced store is G2t[n][c][k].
__global__ __launch_bounds__(256) void k56_mfma(
        const float* __restrict__ agg1, const float* __restrict__ hrb1,
        const ushort* __restrict__ B2t, const float* __restrict__ bias2,
        float* __restrict__ G2t, float* __restrict__ hb2, float* __restrict__ hr2) {
    int t = threadIdx.x;
    int wave = t >> 6, lane = t & 63;
    int quad = lane >> 4, lrow = lane & 15;
    int y = blockIdx.y;
    int n0 = blockIdx.x * 64 + wave * 16;
    int arow = n0 + lrow; if (arow > N_NODES - 1) arow = N_NODES - 1;
    f32x4 acc[4] = {};
    #pragma unroll
    for (int kc = 0; kc < 64; kc += 32) {
        size_t off = (size_t)arow * 64 + kc + quad * 8;
        f32x4 p0 = *(const f32x4*)(agg1 + off);
        f32x4 p1 = *(const f32x4*)(agg1 + off + 4);
        f32x4 q0 = *(const f32x4*)(hrb1 + off);
        f32x4 q1 = *(const f32x4*)(hrb1 + off + 4);
        bfrag a;
        #pragma unroll
        for (int j = 0; j < 4; ++j) {
            a[j]     = (__bf16)fmaxf(p0[j] + q0[j], 0.f);
            a[j + 4] = (__bf16)fmaxf(p1[j] + q1[j], 0.f);
        }
        #pragma unroll
        for (int ct = 0; ct < 4; ++ct) {
            bfrag b = *reinterpret_cast<const bfrag*>(
                B2t + (size_t)(y * 64 + ct * 16 + lrow) * 64 + kc + quad * 8);
            acc[ct] = __builtin_amdgcn_mfma_f32_16x16x32_bf16(a, b, acc[ct], 0, 0, 0);
        }
    }
    #pragma unroll
    for (int ct = 0; ct < 4; ++ct) {
        int cg = y * 64 + ct * 16 + lrow;
        #pragma unroll
        for (int r = 0; r < 4; ++r) {
            int n = n0 + quad * 4 + r;
            if (n >= N_NODES) continue;
            float v = acc[ct][r];
            if (cg < 160)      G2t[(size_t)n * 160 + cg] = v;   // coalesced
            else if (cg < 170) hb2[(size_t)n * 10 + (cg - 160)] = v;
            else if (cg < 180) hr2[(size_t)n * 10 + (cg - 170)] = v + bias2[cg - 170];
        }
    }
}

// ---------------------------------------------------------------------------
// K7: edge pass 2. thread per (edge, class): 10 threads/edge. No fences.
__global__ __launch_bounds__(256) void k7_edge2(
        const float* __restrict__ ea, const int* __restrict__ src_idx,
        const int* __restrict__ dst_idx, const float* __restrict__ G2t,
        const float* __restrict__ hb2, float* __restrict__ agg2) {
    int tid = blockIdx.x * 256 + threadIdx.x;
    if (tid >= N_EDGES * 10) return;
    int e = tid / 10, c = tid - e * 10;
    int s = src_idx[e], d = dst_idx[e];
    float m = hb2[(size_t)s * 10 + c];
    const float* g = G2t + (size_t)s * 160 + c * 16;
    const float* a = ea + (size_t)e * 16;
    f32x4 g0 = *(const f32x4*)g,       g1 = *(const f32x4*)(g + 4);
    f32x4 g2 = *(const f32x4*)(g + 8), g3 = *(const f32x4*)(g + 12);
    f32x4 a0 = *(const f32x4*)a,       a1 = *(const f32x4*)(a + 4);
    f32x4 a2 = *(const f32x4*)(a + 8), a3 = *(const f32x4*)(a + 12);
    #pragma unroll
    for (int k = 0; k < 4; ++k) {
        m = fmaf(a0[k], g0[k], m);
        m = fmaf(a1[k], g1[k], m);
        m = fmaf(a2[k], g2[k], m);
        m = fmaf(a3[k], g3[k], m);
    }
    atomicAdd(&agg2[(size_t)d * 10 + c], m);
}

// ---------------------------------------------------------------------------
// K8: z = agg2 + hr2; out = log_softmax(z)
__global__ void k8_logsoftmax(const float* __restrict__ agg2, const float* __restrict__ hr2,
                              float* __restrict__ out) {
    int n = blockIdx.x * blockDim.x + threadIdx.x;
    if (n >= N_NODES) return;
    float z[10]; float m = -1e30f;
    #pragma unroll
    for (int c = 0; c < 10; ++c) {
        z[c] = agg2[(size_t)n * 10 + c] + hr2[(size_t)n * 10 + c];
        m = fmaxf(m, z[c]);
    }
    float s = 0.f;
    #pragma unroll
    for (int c = 0; c < 10; ++c) s += expf(z[c] - m);
    float ls = logf(s);
    #pragma unroll
    for (int c = 0; c < 10; ++c) out[(size_t)n * 10 + c] = z[c] - m - ls;
}

// ---------------------------------------------------------------------------
extern "C" void kernel_launch(void* const* d_in, const int* in_sizes, int n_in,
                              void* d_out, int out_size, void* d_ws, size_t ws_size,
                              hipStream_t stream) {
    const float* x     = (const float*)d_in[0];
    const float* ea    = (const float*)d_in[1];
    const int*   eidx  = (const int*)d_in[2];
    const float* W1    = (const float*)d_in[3];
    const float* b1    = (const float*)d_in[4];
    const float* We1   = (const float*)d_in[5];
    const float* be1   = (const float*)d_in[6];
    const float* root1 = (const float*)d_in[7];
    const float* bias1 = (const float*)d_in[8];
    const float* We2   = (const float*)d_in[9];
    const float* be2   = (const float*)d_in[10];
    const float* root2 = (const float*)d_in[11];
    const float* bias2 = (const float*)d_in[12];
    float* out = (float*)d_out;

    // workspace layout (float units, all 16B-aligned)
    float* ws = (float*)d_ws;
    ushort* h_bf = (ushort*)ws;                        // 640,000 f
    ushort* B1t  = (ushort*)(ws + 640000);             // 73,728 f
    ushort* B2t  = (ushort*)(ws + 713728);             // 6,144 f
    ushort* G1t  = (ushort*)(ws + 719872);             // 5,120,000 f
    float* hrb1 = ws + 719872 + 5120000;               // 640,000
    float* hb1  = hrb1 + 640000;                       // 640,000
    float* agg1 = hb1  + 640000;                       // 640,000
    float* agg2 = agg1 + 640000;                       // 100,000
    float* G2t  = agg2 + 100000;                       // 1,600,000
    float* hb2  = G2t  + 1600000;                      // 100,000
    float* hr2  = hb2  + 100000;                       // 100,000

    kA_prep<<<KA_B3, 256, 0, stream>>>(x, W1, b1, We1, root1, be1, We2, be2, root2,
                                       h_bf, B1t, B2t);
    k3_mfma<<<dim3(79, 18), 256, 0, stream>>>(h_bf, B1t, bias1, G1t, hrb1, hb1,
                                              agg1, agg2);
    k4_edge1<<<1875, 256, 0, stream>>>(ea, eidx, eidx + N_EDGES, G1t, hb1, agg1);
    k56_mfma<<<dim3(157, 3), 256, 0, stream>>>(agg1, hrb1, B2t, bias2, G2t, hb2, hr2);
    k7_edge2<<<1172, 256, 0, stream>>>(ea, eidx, eidx + N_EDGES, G2t, hb2, agg2);
    k8_logsoftmax<<<40, 256, 0, stream>>>(agg2, hr2, out);
}

// Round 13
// 138.606 us; speedup vs baseline: 1.2605x; 1.0621x over previous
//
#include <hip/hip_runtime.h>

#define N_NODES 10000
#define N_EDGES 30000
#define DIN     64
#define EDIM    16
#define H1      128
#define H2      64
#define C_OUT   10

typedef __bf16 bfrag __attribute__((ext_vector_type(8)));
typedef float  f32x4 __attribute__((ext_vector_type(4)));
typedef ushort ushort8 __attribute__((ext_vector_type(8)));

__device__ __forceinline__ ushort f2bf(float f) {
    union { float f; unsigned u; } x; x.f = f;
    unsigned r = x.u + 0x7fffu + ((x.u >> 16) & 1u);   // RNE; inputs finite
    return (ushort)(r >> 16);
}
__device__ __forceinline__ float bf2f(ushort s) {
    union { unsigned u; float f; } x; x.u = ((unsigned)s) << 16;
    return x.f;
}

// ---------------------------------------------------------------------------
// kA: multi-role prep kernel (block-uniform branch) — R8-proven form:
//   blocks [0,1250):      h = relu(x@W1+b1) -> bf16, 8 nodes/block
//   blocks [1250,1826):   pack B1t[1152][128] bf16, PERMUTED: row c'=o*16+k
//   blocks [1826,1874):   pack B2t[192][64]  bf16, PERMUTED: row c'=c*16+k
#define KA_B1   1250
#define KA_B2   (KA_B1 + 576)
#define KA_B3   (KA_B2 + 48)
__global__ __launch_bounds__(256) void kA_prep(
        const float* __restrict__ x, const float* __restrict__ W1,
        const float* __restrict__ b1,
        const float* __restrict__ We1, const float* __restrict__ root1,
        const float* __restrict__ be1,
        const float* __restrict__ We2, const float* __restrict__ be2,
        const float* __restrict__ root2,
        ushort* __restrict__ h_bf, ushort* __restrict__ B1t,
        ushort* __restrict__ B2t) {
    int t = threadIdx.x;
    int bx = blockIdx.x;
    if (bx < KA_B1) {
        __shared__ float w_lds[DIN * H1];
        __shared__ float b_lds[H1];
        __shared__ float x_lds[8][DIN];
        for (int idx = t; idx < DIN * H1 / 4; idx += 256)
            ((float4*)w_lds)[idx] = ((const float4*)W1)[idx];
        if (t < H1) b_lds[t] = b1[t];
        int n0 = bx * 8;
        if (t < 128) {
            int row = t >> 4, c4 = t & 15;
            int n = n0 + row;
            float4 v = make_float4(0.f, 0.f, 0.f, 0.f);
            if (n < N_NODES) v = ((const float4*)(x + (size_t)n * DIN))[c4];
            ((float4*)(x_lds[row]))[c4] = v;
        }
        __syncthreads();
        int nl = t >> 5;
        int o  = (t & 31) * 4;
        int n  = n0 + nl;
        float4 acc = *(const float4*)&b_lds[o];
        #pragma unroll 8
        for (int i = 0; i < DIN; ++i) {
            float xv = x_lds[nl][i];
            float4 w = *(const float4*)&w_lds[i * H1 + o];
            acc.x = fmaf(xv, w.x, acc.x);
            acc.y = fmaf(xv, w.y, acc.y);
            acc.z = fmaf(xv, w.z, acc.z);
            acc.w = fmaf(xv, w.w, acc.w);
        }
        if (n < N_NODES) {
            ushort4 s;
            s.x = f2bf(fmaxf(acc.x, 0.f));
            s.y = f2bf(fmaxf(acc.y, 0.f));
            s.z = f2bf(fmaxf(acc.z, 0.f));
            s.w = f2bf(fmaxf(acc.w, 0.f));
            *(ushort4*)&h_bf[(size_t)n * H1 + o] = s;
        }
    } else if (bx < KA_B2) {
        int idx = (bx - KA_B1) * 256 + t;
        int c = idx >> 7, i = idx & 127;
        float v;
        if (c < 1024) {
            int o = c >> 4, k = c & 15;              // permuted: c' = o*16 + k
            v = We1[(size_t)k * (H1 * H2) + i * 64 + o];
        } else if (c < 1088) v = root1[i * 64 + (c - 1024)];
        else                 v = be1[i * 64 + (c - 1088)];
        B1t[idx] = f2bf(v);
    } else {
        int idx = (bx - KA_B2) * 256 + t;
        int c = idx >> 6, j = idx & 63;
        float v = 0.f;
        if (c < 160) {
            int cc = c >> 4, k = c & 15;             // permuted: c' = cc*16 + k
            v = We2[(size_t)k * 640 + j * 10 + cc];
        }
        else if (c < 170) v = be2[j * 10 + (c - 160)];
        else if (c < 180) v = root2[j * 10 + (c - 170)];
        B2t[idx] = f2bf(v);
    }
}

// ---------------------------------------------------------------------------
// K3: bf16 MFMA GEMM  C[10000 x 1152] = h_bf @ B1, y-PAIRED: grid (79, 9),
// each block hoists its A-frags to registers once and runs two consecutive
// y column-blocks — halves the h_bf re-fetch vs one-y-per-block. Permuted
// B1t rows make the coalesced direct store the G1t[n][o][k] layout.
// yy==8 blocks (y=16,17) also zero agg1/agg2.
__global__ __launch_bounds__(256) void k3_mfma(
        const ushort* __restrict__ h_bf, const ushort* __restrict__ Bt,
        const float* __restrict__ bias1,
        ushort* __restrict__ G1t, float* __restrict__ hrb1, float* __restrict__ hb1,
        float* __restrict__ agg1, float* __restrict__ agg2) {
    int t = threadIdx.x;
    int wave = t >> 6, lane = t & 63;
    int quad = lane >> 4, lrow = lane & 15;
    int yy = blockIdx.y;           // 0..8 -> y = 2*yy, 2*yy+1
    int mx = blockIdx.x;
    if (yy == 8) {                 // zero agg1 (160000 f4) + agg2 (25000 f4)
        for (int i = mx * 256 + t; i < 160000; i += 79 * 256)
            ((float4*)agg1)[i] = make_float4(0.f, 0.f, 0.f, 0.f);
        for (int i = mx * 256 + t; i < 25000; i += 79 * 256)
            ((float4*)agg2)[i] = make_float4(0.f, 0.f, 0.f, 0.f);
    }
    int nbase = mx * 128 + wave * 32;
    int ar0 = nbase + lrow;       if (ar0 > N_NODES - 1) ar0 = N_NODES - 1;
    int ar1 = nbase + 16 + lrow;  if (ar1 > N_NODES - 1) ar1 = N_NODES - 1;
    // hoist A fragments (8 bfrags = 32 VGPRs), reused across both y
    bfrag A0[4], A1[4];
    #pragma unroll
    for (int kc4 = 0; kc4 < 4; ++kc4) {
        A0[kc4] = *reinterpret_cast<const bfrag*>(
            h_bf + (size_t)ar0 * 128 + kc4 * 32 + quad * 8);
        A1[kc4] = *reinterpret_cast<const bfrag*>(
            h_bf + (size_t)ar1 * 128 + kc4 * 32 + quad * 8);
    }
    #pragma unroll
    for (int hy = 0; hy < 2; ++hy) {
        int y = yy * 2 + hy;
        const ushort* bbase = Bt + (size_t)y * 64 * 128;
        f32x4 acc0[4] = {}, acc1[4] = {};
        #pragma unroll
        for (int kc4 = 0; kc4 < 4; ++kc4) {
            #pragma unroll
            for (int ct = 0; ct < 4; ++ct) {
                bfrag b = *reinterpret_cast<const bfrag*>(
                    bbase + (size_t)(ct * 16 + lrow) * 128 + kc4 * 32 + quad * 8);
                acc0[ct] = __builtin_amdgcn_mfma_f32_16x16x32_bf16(A0[kc4], b, acc0[ct], 0, 0, 0);
                acc1[ct] = __builtin_amdgcn_mfma_f32_16x16x32_bf16(A1[kc4], b, acc1[ct], 0, 0, 0);
            }
        }
        #pragma unroll
        for (int half = 0; half < 2; ++half) {
            int rbase = nbase + half * 16 + quad * 4;
            #pragma unroll
            for (int ct = 0; ct < 4; ++ct) {
                int col = ct * 16 + lrow;
                f32x4 a = half ? acc1[ct] : acc0[ct];
                #pragma unroll
                for (int r = 0; r < 4; ++r) {
                    int n = rbase + r;
                    if (n >= N_NODES) continue;
                    float v = a[r];
                    if (y < 16) {
                        G1t[(size_t)n * 1024 + y * 64 + col] = f2bf(v);  // coalesced
                    } else if (y == 16) {
                        hrb1[(size_t)n * 64 + col] = v + bias1[col];
                    } else {
                        hb1[(size_t)n * 64 + col] = v;
                    }
                }
            }
        }
    }
}

// ---------------------------------------------------------------------------
// K4: edge pass 1 (R8-proven). 2 edges per wave, lane = output o.
// G1t[n][o][k] bf16: per edge, lane reads 32 contiguous bytes (2 x 16B).
__global__ __launch_bounds__(256) void k4_edge1(
        const float* __restrict__ ea, const int* __restrict__ src_idx,
        const int* __restrict__ dst_idx, const ushort* __restrict__ G1t,
        const float* __restrict__ hb1, float* __restrict__ agg1) {
    int t = threadIdx.x;
    int e0 = blockIdx.x * 8 + (t >> 6) * 2;   // 8 edges/block, 2/wave
    int o = t & 63;
    int s0 = src_idx[e0],     d0 = dst_idx[e0];
    int s1 = src_idx[e0 + 1], d1 = dst_idx[e0 + 1];
    const ushort* g0p = G1t + (size_t)s0 * 1024 + o * 16;
    const ushort* g1p = G1t + (size_t)s1 * 1024 + o * 16;
    ushort8 ga0 = *reinterpret_cast<const ushort8*>(g0p);
    ushort8 ga1 = *reinterpret_cast<const ushort8*>(g0p + 8);
    ushort8 gb0 = *reinterpret_cast<const ushort8*>(g1p);
    ushort8 gb1 = *reinterpret_cast<const ushort8*>(g1p + 8);
    float m0 = hb1[(size_t)s0 * 64 + o];
    float m1 = hb1[(size_t)s1 * 64 + o];
    const float* a0 = ea + (size_t)e0 * 16;   // wave-uniform -> scalar loads
    const float* a1 = a0 + 16;
    #pragma unroll
    for (int k = 0; k < 8; ++k) {
        m0 = fmaf(a0[k], bf2f(ga0[k]), m0);
        m1 = fmaf(a1[k], bf2f(gb0[k]), m1);
    }
    #pragma unroll
    for (int k = 0; k < 8; ++k) {
        m0 = fmaf(a0[k + 8], bf2f(ga1[k]), m0);
        m1 = fmaf(a1[k + 8], bf2f(gb1[k]), m1);
    }
    atomicAdd(&agg1[(size_t)d0 * 64 + o], m0);
    atomicAdd(&agg1[(size_t)d1 * 64 + o], m1);
}

// ---------------------------------------------------------------------------
// K56: layer-2 node GEMM via MFMA, A = relu(agg1+hrb1) inline.
// Permuted B2t rows -> direct coalesced store is G2t[n][c][k].
__global__ __launch_bounds__(256) void k56_mfma(
        const float* __restrict__ agg1, const float* __restrict__ hrb1,
        const ushort* __restrict__ B2t, const float* __restrict__ bias2,
        float* __restrict__ G2t, float* __restrict__ hb2, float* __restrict__ hr2) {
    int t = threadIdx.x;
    int wave = t >> 6, lane = t & 63;
    int quad = lane >> 4, lrow = lane & 15;
    int y = blockIdx.y;
    int n0 = blockIdx.x * 64 + wave * 16;
    int arow = n0 + lrow; if (arow > N_NODES - 1) arow = N_NODES - 1;
    f32x4 acc[4] = {};
    #pragma unroll
    for (int kc = 0; kc < 64; kc += 32) {
        size_t off = (size_t)arow * 64 + kc + quad * 8;
        f32x4 p0 = *(const f32x4*)(agg1 + off);
        f32x4 p1 = *(const f32x4*)(agg1 + off + 4);
        f32x4 q0 = *(const f32x4*)(hrb1 + off);
        f32x4 q1 = *(const f32x4*)(hrb1 + off + 4);
        bfrag a;
        #pragma unroll
        for (int j = 0; j < 4; ++j) {
            a[j]     = (__bf16)fmaxf(p0[j] + q0[j], 0.f);
            a[j + 4] = (__bf16)fmaxf(p1[j] + q1[j], 0.f);
        }
        #pragma unroll
        for (int ct = 0; ct < 4; ++ct) {
            bfrag b = *reinterpret_cast<const bfrag*>(
                B2t + (size_t)(y * 64 + ct * 16 + lrow) * 64 + kc + quad * 8);
            acc[ct] = __builtin_amdgcn_mfma_f32_16x16x32_bf16(a, b, acc[ct], 0, 0, 0);
        }
    }
    #pragma unroll
    for (int ct = 0; ct < 4; ++ct) {
        int cg = y * 64 + ct * 16 + lrow;
        #pragma unroll
        for (int r = 0; r < 4; ++r) {
            int n = n0 + quad * 4 + r;
            if (n >= N_NODES) continue;
            float v = acc[ct][r];
            if (cg < 160)      G2t[(size_t)n * 160 + cg] = v;   // coalesced
            else if (cg < 170) hb2[(size_t)n * 10 + (cg - 160)] = v;
            else if (cg < 180) hr2[(size_t)n * 10 + (cg - 170)] = v + bias2[cg - 170];
        }
    }
}

// ---------------------------------------------------------------------------
// K7: edge pass 2. thread per (edge, class): 10 threads/edge. No fences.
__global__ __launch_bounds__(256) void k7_edge2(
        const float* __restrict__ ea, const int* __restrict__ src_idx,
        const int* __restrict__ dst_idx, const float* __restrict__ G2t,
        const float* __restrict__ hb2, float* __restrict__ agg2) {
    int tid = blockIdx.x * 256 + threadIdx.x;
    if (tid >= N_EDGES * 10) return;
    int e = tid / 10, c = tid - e * 10;
    int s = src_idx[e], d = dst_idx[e];
    float m = hb2[(size_t)s * 10 + c];
    const float* g = G2t + (size_t)s * 160 + c * 16;
    const float* a = ea + (size_t)e * 16;
    f32x4 g0 = *(const f32x4*)g,       g1 = *(const f32x4*)(g + 4);
    f32x4 g2 = *(const f32x4*)(g + 8), g3 = *(const f32x4*)(g + 12);
    f32x4 a0 = *(const f32x4*)a,       a1 = *(const f32x4*)(a + 4);
    f32x4 a2 = *(const f32x4*)(a + 8), a3 = *(const f32x4*)(a + 12);
    #pragma unroll
    for (int k = 0; k < 4; ++k) {
        m = fmaf(a0[k], g0[k], m);
        m = fmaf(a1[k], g1[k], m);
        m = fmaf(a2[k], g2[k], m);
        m = fmaf(a3[k], g3[k], m);
    }
    atomicAdd(&agg2[(size_t)d * 10 + c], m);
}

// ---------------------------------------------------------------------------
// K8: z = agg2 + hr2; out = log_softmax(z)
__global__ void k8_logsoftmax(const float* __restrict__ agg2, const float* __restrict__ hr2,
                              float* __restrict__ out) {
    int n = blockIdx.x * blockDim.x + threadIdx.x;
    if (n >= N_NODES) return;
    float z[10]; float m = -1e30f;
    #pragma unroll
    for (int c = 0; c < 10; ++c) {
        z[c] = agg2[(size_t)n * 10 + c] + hr2[(size_t)n * 10 + c];
        m = fmaxf(m, z[c]);
    }
    float s = 0.f;
    #pragma unroll
    for (int c = 0; c < 10; ++c) s += expf(z[c] - m);
    float ls = logf(s);
    #pragma unroll
    for (int c = 0; c < 10; ++c) out[(size_t)n * 10 + c] = z[c] - m - ls;
}

// ---------------------------------------------------------------------------
extern "C" void kernel_launch(void* const* d_in, const int* in_sizes, int n_in,
                              void* d_out, int out_size, void* d_ws, size_t ws_size,
                              hipStream_t stream) {
    const float* x     = (const float*)d_in[0];
    const float* ea    = (const float*)d_in[1];
    const int*   eidx  = (const int*)d_in[2];
    const float* W1    = (const float*)d_in[3];
    const float* b1    = (const float*)d_in[4];
    const float* We1   = (const float*)d_in[5];
    const float* be1   = (const float*)d_in[6];
    const float* root1 = (const float*)d_in[7];
    const float* bias1 = (const float*)d_in[8];
    const float* We2   = (const float*)d_in[9];
    const float* be2   = (const float*)d_in[10];
    const float* root2 = (const float*)d_in[11];
    const float* bias2 = (const float*)d_in[12];
    float* out = (float*)d_out;

    // workspace layout (float units, all 16B-aligned)
    float* ws = (float*)d_ws;
    ushort* h_bf = (ushort*)ws;                        // 640,000 f
    ushort* B1t  = (ushort*)(ws + 640000);             // 73,728 f
    ushort* B2t  = (ushort*)(ws + 713728);             // 6,144 f
    ushort* G1t  = (ushort*)(ws + 719872);             // 5,120,000 f
    float* hrb1 = ws + 719872 + 5120000;               // 640,000
    float* hb1  = hrb1 + 640000;                       // 640,000
    float* agg1 = hb1  + 640000;                       // 640,000
    float* agg2 = agg1 + 640000;                       // 100,000
    float* G2t  = agg2 + 100000;                       // 1,600,000
    float* hb2  = G2t  + 1600000;                      // 100,000
    float* hr2  = hb2  + 100000;                       // 100,000

    kA_prep<<<KA_B3, 256, 0, stream>>>(x, W1, b1, We1, root1, be1, We2, be2, root2,
                                       h_bf, B1t, B2t);
    k3_mfma<<<dim3(79, 9), 256, 0, stream>>>(h_bf, B1t, bias1, G1t, hrb1, hb1,
                                             agg1, agg2);
    k4_edge1<<<3750, 256, 0, stream>>>(ea, eidx, eidx + N_EDGES, G1t, hb1, agg1);
    k56_mfma<<<dim3(157, 3), 256, 0, stream>>>(agg1, hrb1, B2t, bias2, G2t, hb2, hr2);
    k7_edge2<<<1172, 256, 0, stream>>>(ea, eidx, eidx + N_EDGES, G2t, hb2, agg2);
    k8_logsoftmax<<<40, 256, 0, stream>>>(agg2, hr2, out);
}

// Round 14
// 137.554 us; speedup vs baseline: 1.2701x; 1.0077x over previous
//
#include <hip/hip_runtime.h>

#define N_NODES 10000
#define N_EDGES 30000
#define DIN     64
#define EDIM    16
#define H1      128
#define H2      64
#define C_OUT   10

typedef __bf16 bfrag __attribute__((ext_vector_type(8)));
typedef float  f32x4 __attribute__((ext_vector_type(4)));
typedef ushort ushort8 __attribute__((ext_vector_type(8)));

__device__ __forceinline__ ushort f2bf(float f) {
    union { float f; unsigned u; } x; x.f = f;
    unsigned r = x.u + 0x7fffu + ((x.u >> 16) & 1u);   // RNE; inputs finite
    return (ushort)(r >> 16);
}
__device__ __forceinline__ float bf2f(ushort s) {
    union { unsigned u; float f; } x; x.u = ((unsigned)s) << 16;
    return x.f;
}

// ---------------------------------------------------------------------------
// kA: multi-role prep kernel (block-uniform branch) — R8-proven form.
#define KA_B1   1250
#define KA_B2   (KA_B1 + 576)
#define KA_B3   (KA_B2 + 48)
__global__ __launch_bounds__(256) void kA_prep(
        const float* __restrict__ x, const float* __restrict__ W1,
        const float* __restrict__ b1,
        const float* __restrict__ We1, const float* __restrict__ root1,
        const float* __restrict__ be1,
        const float* __restrict__ We2, const float* __restrict__ be2,
        const float* __restrict__ root2,
        ushort* __restrict__ h_bf, ushort* __restrict__ B1t,
        ushort* __restrict__ B2t) {
    int t = threadIdx.x;
    int bx = blockIdx.x;
    if (bx < KA_B1) {
        __shared__ float w_lds[DIN * H1];
        __shared__ float b_lds[H1];
        __shared__ float x_lds[8][DIN];
        for (int idx = t; idx < DIN * H1 / 4; idx += 256)
            ((float4*)w_lds)[idx] = ((const float4*)W1)[idx];
        if (t < H1) b_lds[t] = b1[t];
        int n0 = bx * 8;
        if (t < 128) {
            int row = t >> 4, c4 = t & 15;
            int n = n0 + row;
            float4 v = make_float4(0.f, 0.f, 0.f, 0.f);
            if (n < N_NODES) v = ((const float4*)(x + (size_t)n * DIN))[c4];
            ((float4*)(x_lds[row]))[c4] = v;
        }
        __syncthreads();
        int nl = t >> 5;
        int o  = (t & 31) * 4;
        int n  = n0 + nl;
        float4 acc = *(const float4*)&b_lds[o];
        #pragma unroll 8
        for (int i = 0; i < DIN; ++i) {
            float xv = x_lds[nl][i];
            float4 w = *(const float4*)&w_lds[i * H1 + o];
            acc.x = fmaf(xv, w.x, acc.x);
            acc.y = fmaf(xv, w.y, acc.y);
            acc.z = fmaf(xv, w.z, acc.z);
            acc.w = fmaf(xv, w.w, acc.w);
        }
        if (n < N_NODES) {
            ushort4 s;
            s.x = f2bf(fmaxf(acc.x, 0.f));
            s.y = f2bf(fmaxf(acc.y, 0.f));
            s.z = f2bf(fmaxf(acc.z, 0.f));
            s.w = f2bf(fmaxf(acc.w, 0.f));
            *(ushort4*)&h_bf[(size_t)n * H1 + o] = s;
        }
    } else if (bx < KA_B2) {
        int idx = (bx - KA_B1) * 256 + t;
        int c = idx >> 7, i = idx & 127;
        float v;
        if (c < 1024) {
            int o = c >> 4, k = c & 15;              // permuted: c' = o*16 + k
            v = We1[(size_t)k * (H1 * H2) + i * 64 + o];
        } else if (c < 1088) v = root1[i * 64 + (c - 1024)];
        else                 v = be1[i * 64 + (c - 1088)];
        B1t[idx] = f2bf(v);
    } else {
        int idx = (bx - KA_B2) * 256 + t;
        int c = idx >> 6, j = idx & 63;
        float v = 0.f;
        if (c < 160) {
            int cc = c >> 4, k = c & 15;             // permuted: c' = cc*16 + k
            v = We2[(size_t)k * 640 + j * 10 + cc];
        }
        else if (c < 170) v = be2[j * 10 + (c - 160)];
        else if (c < 180) v = root2[j * 10 + (c - 170)];
        B2t[idx] = f2bf(v);
    }
}

// ---------------------------------------------------------------------------
// K3: bf16 MFMA GEMM, y-TRIPLED: grid (79, 6), block hoists A-frags once and
// runs 3 consecutive y column-blocks (A-refetch 18x -> 6x vs one-y-per-block).
// Permuted B1t rows -> coalesced direct store is G1t[n][o][k].
// yy==5 blocks (y=15,16,17) also zero agg1/agg2.
__global__ __launch_bounds__(256) void k3_mfma(
        const ushort* __restrict__ h_bf, const ushort* __restrict__ Bt,
        const float* __restrict__ bias1,
        ushort* __restrict__ G1t, float* __restrict__ hrb1, float* __restrict__ hb1,
        float* __restrict__ agg1, float* __restrict__ agg2) {
    int t = threadIdx.x;
    int wave = t >> 6, lane = t & 63;
    int quad = lane >> 4, lrow = lane & 15;
    int yy = blockIdx.y;           // 0..5 -> y = 3*yy + {0,1,2}
    int mx = blockIdx.x;
    if (yy == 5) {                 // zero agg1 (160000 f4) + agg2 (25000 f4)
        for (int i = mx * 256 + t; i < 160000; i += 79 * 256)
            ((float4*)agg1)[i] = make_float4(0.f, 0.f, 0.f, 0.f);
        for (int i = mx * 256 + t; i < 25000; i += 79 * 256)
            ((float4*)agg2)[i] = make_float4(0.f, 0.f, 0.f, 0.f);
    }
    int nbase = mx * 128 + wave * 32;
    int ar0 = nbase + lrow;       if (ar0 > N_NODES - 1) ar0 = N_NODES - 1;
    int ar1 = nbase + 16 + lrow;  if (ar1 > N_NODES - 1) ar1 = N_NODES - 1;
    // hoist A fragments (8 bfrags = 32 VGPRs), reused across 3 y
    bfrag A0[4], A1[4];
    #pragma unroll
    for (int kc4 = 0; kc4 < 4; ++kc4) {
        A0[kc4] = *reinterpret_cast<const bfrag*>(
            h_bf + (size_t)ar0 * 128 + kc4 * 32 + quad * 8);
        A1[kc4] = *reinterpret_cast<const bfrag*>(
            h_bf + (size_t)ar1 * 128 + kc4 * 32 + quad * 8);
    }
    #pragma unroll
    for (int hy = 0; hy < 3; ++hy) {
        int y = yy * 3 + hy;
        const ushort* bbase = Bt + (size_t)y * 64 * 128;
        f32x4 acc0[4] = {}, acc1[4] = {};
        #pragma unroll
        for (int kc4 = 0; kc4 < 4; ++kc4) {
            #pragma unroll
            for (int ct = 0; ct < 4; ++ct) {
                bfrag b = *reinterpret_cast<const bfrag*>(
                    bbase + (size_t)(ct * 16 + lrow) * 128 + kc4 * 32 + quad * 8);
                acc0[ct] = __builtin_amdgcn_mfma_f32_16x16x32_bf16(A0[kc4], b, acc0[ct], 0, 0, 0);
                acc1[ct] = __builtin_amdgcn_mfma_f32_16x16x32_bf16(A1[kc4], b, acc1[ct], 0, 0, 0);
            }
        }
        #pragma unroll
        for (int half = 0; half < 2; ++half) {
            int rbase = nbase + half * 16 + quad * 4;
            #pragma unroll
            for (int ct = 0; ct < 4; ++ct) {
                int col = ct * 16 + lrow;
                f32x4 a = half ? acc1[ct] : acc0[ct];
                #pragma unroll
                for (int r = 0; r < 4; ++r) {
                    int n = rbase + r;
                    if (n >= N_NODES) continue;
                    float v = a[r];
                    if (y < 16) {
                        G1t[(size_t)n * 1024 + y * 64 + col] = f2bf(v);  // coalesced
                    } else if (y == 16) {
                        hrb1[(size_t)n * 64 + col] = v + bias1[col];
                    } else {
                        hb1[(size_t)n * 64 + col] = v;
                    }
                }
            }
        }
    }
}

// ---------------------------------------------------------------------------
// K4: edge pass 1 (R8-proven). 2 edges per wave, lane = output o.
// G1t[n][o][k] bf16: per edge, lane reads 32 contiguous bytes (2 x 16B).
__global__ __launch_bounds__(256) void k4_edge1(
        const float* __restrict__ ea, const int* __restrict__ src_idx,
        const int* __restrict__ dst_idx, const ushort* __restrict__ G1t,
        const float* __restrict__ hb1, float* __restrict__ agg1) {
    int t = threadIdx.x;
    int e0 = blockIdx.x * 8 + (t >> 6) * 2;   // 8 edges/block, 2/wave
    int o = t & 63;
    int s0 = src_idx[e0],     d0 = dst_idx[e0];
    int s1 = src_idx[e0 + 1], d1 = dst_idx[e0 + 1];
    const ushort* g0p = G1t + (size_t)s0 * 1024 + o * 16;
    const ushort* g1p = G1t + (size_t)s1 * 1024 + o * 16;
    ushort8 ga0 = *reinterpret_cast<const ushort8*>(g0p);
    ushort8 ga1 = *reinterpret_cast<const ushort8*>(g0p + 8);
    ushort8 gb0 = *reinterpret_cast<const ushort8*>(g1p);
    ushort8 gb1 = *reinterpret_cast<const ushort8*>(g1p + 8);
    float m0 = hb1[(size_t)s0 * 64 + o];
    float m1 = hb1[(size_t)s1 * 64 + o];
    const float* a0 = ea + (size_t)e0 * 16;   // wave-uniform -> scalar loads
    const float* a1 = a0 + 16;
    #pragma unroll
    for (int k = 0; k < 8; ++k) {
        m0 = fmaf(a0[k], bf2f(ga0[k]), m0);
        m1 = fmaf(a1[k], bf2f(gb0[k]), m1);
    }
    #pragma unroll
    for (int k = 0; k < 8; ++k) {
        m0 = fmaf(a0[k + 8], bf2f(ga1[k]), m0);
        m1 = fmaf(a1[k + 8], bf2f(gb1[k]), m1);
    }
    atomicAdd(&agg1[(size_t)d0 * 64 + o], m0);
    atomicAdd(&agg1[(size_t)d1 * 64 + o], m1);
}

// ---------------------------------------------------------------------------
// K56: layer-2 node GEMM via MFMA, y-MERGED: grid (157), block loads A
// (relu(agg1+hrb1) inline) once and runs all 3 y-slices off it.
// Permuted B2t rows -> direct coalesced store is G2t[n][c][k].
__global__ __launch_bounds__(256) void k56_mfma(
        const float* __restrict__ agg1, const float* __restrict__ hrb1,
        const ushort* __restrict__ B2t, const float* __restrict__ bias2,
        float* __restrict__ G2t, float* __restrict__ hb2, float* __restrict__ hr2) {
    int t = threadIdx.x;
    int wave = t >> 6, lane = t & 63;
    int quad = lane >> 4, lrow = lane & 15;
    int n0 = blockIdx.x * 64 + wave * 16;
    int arow = n0 + lrow; if (arow > N_NODES - 1) arow = N_NODES - 1;
    // load A fragments once (2 bfrags)
    bfrag A[2];
    #pragma unroll
    for (int kk = 0; kk < 2; ++kk) {
        size_t off = (size_t)arow * 64 + kk * 32 + quad * 8;
        f32x4 p0 = *(const f32x4*)(agg1 + off);
        f32x4 p1 = *(const f32x4*)(agg1 + off + 4);
        f32x4 q0 = *(const f32x4*)(hrb1 + off);
        f32x4 q1 = *(const f32x4*)(hrb1 + off + 4);
        bfrag a;
        #pragma unroll
        for (int j = 0; j < 4; ++j) {
            a[j]     = (__bf16)fmaxf(p0[j] + q0[j], 0.f);
            a[j + 4] = (__bf16)fmaxf(p1[j] + q1[j], 0.f);
        }
        A[kk] = a;
    }
    #pragma unroll
    for (int y = 0; y < 3; ++y) {
        f32x4 acc[4] = {};
        #pragma unroll
        for (int kk = 0; kk < 2; ++kk) {
            #pragma unroll
            for (int ct = 0; ct < 4; ++ct) {
                bfrag b = *reinterpret_cast<const bfrag*>(
                    B2t + (size_t)(y * 64 + ct * 16 + lrow) * 64 + kk * 32 + quad * 8);
                acc[ct] = __builtin_amdgcn_mfma_f32_16x16x32_bf16(A[kk], b, acc[ct], 0, 0, 0);
            }
        }
        #pragma unroll
        for (int ct = 0; ct < 4; ++ct) {
            int cg = y * 64 + ct * 16 + lrow;
            #pragma unroll
            for (int r = 0; r < 4; ++r) {
                int n = n0 + quad * 4 + r;
                if (n >= N_NODES) continue;
                float v = acc[ct][r];
                if (cg < 160)      G2t[(size_t)n * 160 + cg] = v;   // coalesced
                else if (cg < 170) hb2[(size_t)n * 10 + (cg - 160)] = v;
                else if (cg < 180) hr2[(size_t)n * 10 + (cg - 170)] = v + bias2[cg - 170];
            }
        }
    }
}

// ---------------------------------------------------------------------------
// K7: edge pass 2. thread per (edge, class): 10 threads/edge. No fences.
__global__ __launch_bounds__(256) void k7_edge2(
        const float* __restrict__ ea, const int* __restrict__ src_idx,
        const int* __restrict__ dst_idx, const float* __restrict__ G2t,
        const float* __restrict__ hb2, float* __restrict__ agg2) {
    int tid = blockIdx.x * 256 + threadIdx.x;
    if (tid >= N_EDGES * 10) return;
    int e = tid / 10, c = tid - e * 10;
    int s = src_idx[e], d = dst_idx[e];
    float m = hb2[(size_t)s * 10 + c];
    const float* g = G2t + (size_t)s * 160 + c * 16;
    const float* a = ea + (size_t)e * 16;
    f32x4 g0 = *(const f32x4*)g,       g1 = *(const f32x4*)(g + 4);
    f32x4 g2 = *(const f32x4*)(g + 8), g3 = *(const f32x4*)(g + 12);
    f32x4 a0 = *(const f32x4*)a,       a1 = *(const f32x4*)(a + 4);
    f32x4 a2 = *(const f32x4*)(a + 8), a3 = *(const f32x4*)(a + 12);
    #pragma unroll
    for (int k = 0; k < 4; ++k) {
        m = fmaf(a0[k], g0[k], m);
        m = fmaf(a1[k], g1[k], m);
        m = fmaf(a2[k], g2[k], m);
        m = fmaf(a3[k], g3[k], m);
    }
    atomicAdd(&agg2[(size_t)d * 10 + c], m);
}

// ---------------------------------------------------------------------------
// K8: z = agg2 + hr2; out = log_softmax(z)
__global__ void k8_logsoftmax(const float* __restrict__ agg2, const float* __restrict__ hr2,
                              float* __restrict__ out) {
    int n = blockIdx.x * blockDim.x + threadIdx.x;
    if (n >= N_NODES) return;
    float z[10]; float m = -1e30f;
    #pragma unroll
    for (int c = 0; c < 10; ++c) {
        z[c] = agg2[(size_t)n * 10 + c] + hr2[(size_t)n * 10 + c];
        m = fmaxf(m, z[c]);
    }
    float s = 0.f;
    #pragma unroll
    for (int c = 0; c < 10; ++c) s += expf(z[c] - m);
    float ls = logf(s);
    #pragma unroll
    for (int c = 0; c < 10; ++c) out[(size_t)n * 10 + c] = z[c] - m - ls;
}

// ---------------------------------------------------------------------------
extern "C" void kernel_launch(void* const* d_in, const int* in_sizes, int n_in,
                              void* d_out, int out_size, void* d_ws, size_t ws_size,
                              hipStream_t stream) {
    const float* x     = (const float*)d_in[0];
    const float* ea    = (const float*)d_in[1];
    const int*   eidx  = (const int*)d_in[2];
    const float* W1    = (const float*)d_in[3];
    const float* b1    = (const float*)d_in[4];
    const float* We1   = (const float*)d_in[5];
    const float* be1   = (const float*)d_in[6];
    const float* root1 = (const float*)d_in[7];
    const float* bias1 = (const float*)d_in[8];
    const float* We2   = (const float*)d_in[9];
    const float* be2   = (const float*)d_in[10];
    const float* root2 = (const float*)d_in[11];
    const float* bias2 = (const float*)d_in[12];
    float* out = (float*)d_out;

    // workspace layout (float units, all 16B-aligned)
    float* ws = (float*)d_ws;
    ushort* h_bf = (ushort*)ws;                        // 640,000 f
    ushort* B1t  = (ushort*)(ws + 640000);             // 73,728 f
    ushort* B2t  = (ushort*)(ws + 713728);             // 6,144 f
    ushort* G1t  = (ushort*)(ws + 719872);             // 5,120,000 f
    float* hrb1 = ws + 719872 + 5120000;               // 640,000
    float* hb1  = hrb1 + 640000;                       // 640,000
    float* agg1 = hb1  + 640000;                       // 640,000
    float* agg2 = agg1 + 640000;                       // 100,000
    float* G2t  = agg2 + 100000;                       // 1,600,000
    float* hb2  = G2t  + 1600000;                      // 100,000
    float* hr2  = hb2  + 100000;                       // 100,000

    kA_prep<<<KA_B3, 256, 0, stream>>>(x, W1, b1, We1, root1, be1, We2, be2, root2,
                                       h_bf, B1t, B2t);
    k3_mfma<<<dim3(79, 6), 256, 0, stream>>>(h_bf, B1t, bias1, G1t, hrb1, hb1,
                                             agg1, agg2);
    k4_edge1<<<3750, 256, 0, stream>>>(ea, eidx, eidx + N_EDGES, G1t, hb1, agg1);
    k56_mfma<<<157, 256, 0, stream>>>(agg1, hrb1, B2t, bias2, G2t, hb2, hr2);
    k7_edge2<<<1172, 256, 0, stream>>>(ea, eidx, eidx + N_EDGES, G2t, hb2, agg2);
    k8_logsoftmax<<<40, 256, 0, stream>>>(agg2, hr2, out);
}